// Round 10
// baseline (12234.012 us; speedup 1.0000x reference)
//
#include <hip/hip_runtime.h>
#include <math.h>

#define B_  2048
#define S_  32
#define T_  32
#define D_  128
#define H_  256
#define G3  768
#define VT_ 256
#define BOW_ 1

typedef __attribute__((ext_vector_type(8))) short short8;
typedef __attribute__((ext_vector_type(4))) float f32x4;
typedef __attribute__((ext_vector_type(8))) unsigned short us8;
typedef unsigned short u16;

#define MFMA16 __builtin_amdgcn_mfma_f32_16x16x32_bf16

__device__ inline u16 f2bf(float x) {
  union { float f; unsigned u; } v; v.f = x;
  unsigned r = v.u + 0x7FFFu + ((v.u >> 16) & 1u);
  return (u16)(r >> 16);
}
__device__ inline float bf2f(u16 b) {
  union { unsigned u; float f; } v; v.u = ((unsigned)b) << 16; return v.f;
}
__device__ inline int swz(int r) { return ((r ^ (r >> 3)) & 7) << 3; }
// swizzled u16 index within a [16][256] plane
__device__ inline int psl(int row, int j) {
  return row * 256 + ((((j >> 3) ^ (row & 7)) << 3) | (j & 7));
}
__device__ inline float sigm(float x) { return 1.f / (1.f + expf(-x)); }

// ---------------- weight transpose + split ----------------
struct TMat { const float* src; u16* dhi; u16* dlo; int R; int C; int tile0; };
struct TPack { TMat m[10]; };

__global__ __launch_bounds__(256)
void wsplit_t(TPack P) {
  int bx = blockIdx.x;
  TMat M = P.m[0];
  #pragma unroll
  for (int i = 1; i < 10; i++) if (bx >= P.m[i].tile0) M = P.m[i];
  int ti = bx - M.tile0;
  int tilesR = M.R >> 6;
  int rt = ti % tilesR, ct = ti / tilesR;
  int r0 = rt * 64, c0 = ct * 64;
  __shared__ float ts[64][65];
  int tid = threadIdx.x;
  int cx = tid & 63, ry = tid >> 6;
  #pragma unroll
  for (int i = 0; i < 16; i++) {
    int r = ry * 16 + i;
    ts[r][cx] = M.src[(size_t)(r0 + r) * M.C + c0 + cx];
  }
  __syncthreads();
  int rx = tid & 63, cy = tid >> 6;
  #pragma unroll
  for (int i = 0; i < 16; i++) {
    int cc = cy * 16 + i;
    float v = ts[rx][cc];
    u16 hi = f2bf(v);
    size_t o = (size_t)(c0 + cc) * M.R + r0 + rx;
    M.dhi[o] = hi;
    M.dlo[o] = f2bf(v - bf2f(hi));
  }
}

__global__ __launch_bounds__(256)
void esplit(const float* a, const float* b, u16* ah, u16* al, u16* bh, u16* bl, int n) {
  int i = blockIdx.x * 256 + threadIdx.x;
  if (i >= 2 * n) return;
  const float* s = (i < n) ? a : b;
  u16* dh = (i < n) ? ah : bh;
  u16* dl = (i < n) ? al : bl;
  int j = (i < n) ? i : i - n;
  float v = s[j];
  u16 hi = f2bf(v);
  dh[j] = hi; dl[j] = f2bf(v - bf2f(hi));
}

// ---------------- plane GEMM (tables / proj / logits) ----------------
struct PLeg {
  const u16* Ahi; const u16* Alo; int lda;
  const u16* Bthi; const u16* Btlo; int ldb;
  const float* bias; void* C; int ldc; int cmode;  // 0=f32, 1=bf16, 2=logits-layout
  int M, N, K;
};

__global__ __launch_bounds__(256)
void gemm_pl(PLeg l0, PLeg l1) {
  PLeg L = blockIdx.z ? l1 : l0;
  int n0 = blockIdx.x * 128; if (n0 >= L.N) return;
  int m0 = blockIdx.y * 128; if (m0 >= L.M) return;
  __shared__ u16 As[128 * 64];
  __shared__ u16 Bs[128 * 64];
  int tid = threadIdx.x;
  int lane = tid & 63, wv = tid >> 6;
  int wr = (wv >> 1) * 64, wc = (wv & 1) * 64;
  int fr = lane & 15, fk = (lane >> 4) * 8;
  f32x4 acc[4][4];
  #pragma unroll
  for (int m = 0; m < 4; m++)
    #pragma unroll
    for (int n = 0; n < 4; n++) acc[m][n] = (f32x4){0.f, 0.f, 0.f, 0.f};

  int s_row = tid >> 1, s_part = tid & 1;

  for (int k0 = 0; k0 < L.K; k0 += 32) {
    if (k0) __syncthreads();
    int swA = swz(s_row);
    {
      const u16* src = (s_part ? L.Alo : L.Ahi) + (size_t)(m0 + s_row) * L.lda + k0;
      #pragma unroll
      for (int q = 0; q < 4; q++)
        *(us8*)&As[(s_row * 64 + s_part * 32 + q * 8) ^ swA] = *(const us8*)(src + q * 8);
    }
    {
      const u16* src = (s_part ? L.Btlo : L.Bthi) + (size_t)(n0 + s_row) * L.ldb + k0;
      #pragma unroll
      for (int q = 0; q < 4; q++)
        *(us8*)&Bs[(s_row * 64 + s_part * 32 + q * 8) ^ swA] = *(const us8*)(src + q * 8);
    }
    __syncthreads();
    short8 bhi[4], blo[4];
    #pragma unroll
    for (int n = 0; n < 4; n++) {
      int cc = wc + n * 16 + fr; int sw = swz(cc);
      bhi[n] = *(const short8*)&Bs[(cc * 64 + fk) ^ sw];
      blo[n] = *(const short8*)&Bs[(cc * 64 + 32 + fk) ^ sw];
    }
    #pragma unroll
    for (int m = 0; m < 4; m++) {
      int r = wr + m * 16 + fr; int sw = swz(r);
      short8 ahi = *(const short8*)&As[(r * 64 + fk) ^ sw];
      short8 alo = *(const short8*)&As[(r * 64 + 32 + fk) ^ sw];
      #pragma unroll
      for (int n = 0; n < 4; n++) {
        acc[m][n] = MFMA16(ahi, bhi[n], acc[m][n], 0, 0, 0);
        acc[m][n] = MFMA16(ahi, blo[n], acc[m][n], 0, 0, 0);
        acc[m][n] = MFMA16(alo, bhi[n], acc[m][n], 0, 0, 0);
      }
    }
  }
  int rbase = (lane >> 4) * 4;
  #pragma unroll
  for (int m = 0; m < 4; m++)
    #pragma unroll
    for (int rr = 0; rr < 4; rr++) {
      int row = m0 + wr + m * 16 + rbase + rr;
      #pragma unroll
      for (int n = 0; n < 4; n++) {
        int col = n0 + wc + n * 16 + fr;
        float v = acc[m][n][rr];
        if (L.bias) v += L.bias[col];
        if (L.cmode == 0)      ((float*)L.C)[(size_t)row * L.ldc + col] = v;
        else if (L.cmode == 1) ((u16*)L.C)[(size_t)row * L.ldc + col] = f2bf(v);
        else {
          size_t o = (((size_t)(row & (B_ - 1))) * T_ + (row >> 11)) * VT_ + col;
          ((float*)L.C)[o] = v;
        }
      }
    }
}

// ================= monolithic encoder: 256 blocks x 8 rows, both dirs =================
struct EncMP {
  const u16 *UH0, *UL0, *UH1, *UL1;
  const float *gxT0, *gxT1;
  const float *bias0, *bias1;
  u16 *ssH, *ssL;
  const int *ids;
};

__global__ __launch_bounds__(256, 1)
void enc_mono(EncMP P) {
  __shared__ __align__(16) u16 hPl[2][2][4096];   // [dir][plane][16*256], swizzled
  __shared__ float hF[2][2048];                   // [dir][8*256]
  __shared__ int ids_l[256];
  const int tid = threadIdx.x;
  const int lane = tid & 63, wv = tid >> 6;
  const int fr = lane & 15, kq = lane >> 4;
  const int jb = wv * 64;
  const int r0 = blockIdx.x * 8;

  {
    us8 z8 = {0,0,0,0,0,0,0,0};
    us8* pb = (us8*)&hPl[0][0][0];
    #pragma unroll
    for (int i = 0; i < 8; i++) pb[i * 256 + tid] = z8;   // 2048 us8 = 32KB
    f32x4 zf = {0.f,0.f,0.f,0.f};
    f32x4* fb = (f32x4*)&hF[0][0];
    #pragma unroll
    for (int i = 0; i < 4; i++) fb[i * 256 + tid] = zf;
  }
  ids_l[tid] = P.ids[(r0 + (tid >> 5)) * S_ + (tid & 31)];
  __syncthreads();

  float bz[2][4], br[2][4], bxc[2][4], bhc[2][4];
  #pragma unroll
  for (int d = 0; d < 2; d++) {
    const float* b0 = d ? P.bias1 : P.bias0;
    const float* b1 = b0 + G3;
    #pragma unroll
    for (int nt = 0; nt < 4; nt++) {
      int j = jb + nt * 16 + fr;
      bz[d][nt]  = b0[j] + b1[j];
      br[d][nt]  = b0[256 + j] + b1[256 + j];
      bxc[d][nt] = b0[512 + j];
      bhc[d][nt] = b1[512 + j];
    }
  }

  for (int s = 0; s < S_; s++) {
    #pragma unroll 1
    for (int d = 0; d < 2; d++) {
      const u16* UH = d ? P.UH1 : P.UH0;
      const u16* UL = d ? P.UL1 : P.UL0;
      const float* gxT = d ? P.gxT1 : P.gxT0;
      u16* hp0 = hPl[d][0];
      u16* hp1 = hPl[d][1];
      f32x4 acc[3][4];
      #pragma unroll
      for (int a = 0; a < 3; a++)
        #pragma unroll
        for (int nt = 0; nt < 4; nt++) acc[a][nt] = (f32x4){0.f,0.f,0.f,0.f};

      #pragma unroll
      for (int i = 0; i < 8; i++) {
        int slot = (((i * 4 + kq) ^ (fr & 7)) << 3);
        short8 ah = *(const short8*)&hp0[fr * 256 + slot];
        short8 al = *(const short8*)&hp1[fr * 256 + slot];
        #pragma unroll
        for (int st = 0; st < 3; st++)
          #pragma unroll
          for (int nt = 0; nt < 4; nt++) {
            size_t ro = (size_t)(st * 256 + jb + nt * 16 + fr) * 256 + i * 32 + kq * 8;
            short8 bh = *(const short8*)(UH + ro);
            short8 bl = *(const short8*)(UL + ro);
            acc[st][nt] = MFMA16(ah, bh, acc[st][nt], 0, 0, 0);
            acc[st][nt] = MFMA16(ah, bl, acc[st][nt], 0, 0, 0);
            acc[st][nt] = MFMA16(al, bh, acc[st][nt], 0, 0, 0);
          }
      }
      __syncthreads();
      if (kq < 2) {
        #pragma unroll
        for (int rr = 0; rr < 4; rr++) {
          int row = kq * 4 + rr;
          int gb = r0 + row;
          int id = ids_l[row * 32 + (d ? (31 - s) : s)];
          const float* T = gxT + (size_t)id * G3;
          int pos = d ? (31 - s) : s;
          #pragma unroll
          for (int nt = 0; nt < 4; nt++) {
            int j = jb + nt * 16 + fr;
            float z = sigm(acc[0][nt][rr] + T[j] + bz[d][nt]);
            float r = sigm(acc[1][nt][rr] + T[256 + j] + br[d][nt]);
            float c = tanhf(T[512 + j] + bxc[d][nt] + r * (acc[2][nt][rr] + bhc[d][nt]));
            float hp = hF[d][row * 256 + j];
            float hn = z * hp + (1.f - z) * c;
            hF[d][row * 256 + j] = hn;
            u16 hi = f2bf(hn);
            u16 lo = f2bf(hn - bf2f(hi));
            int ps = psl(row, j);
            hp0[ps] = hi; hp1[ps] = lo;
            size_t o = ((size_t)pos * B_ + gb) * 256 + j;
            if (s < 16) {
              P.ssH[o] = hi; P.ssL[o] = lo;
            } else {
              float v = bf2f(P.ssH[o]) + bf2f(P.ssL[o]) + hn;
              u16 vh = f2bf(v);
              P.ssH[o] = vh; P.ssL[o] = f2bf(v - bf2f(vh));
            }
          }
        }
      }
      __syncthreads();
    }
  }
}

// ================= monolithic decoder: 256 blocks x 8 rows =================
struct DecMP {
  const u16 *UH, *UL, *CH, *CL;
  const float *gxT;
  const float *bias;
  const u16 *sWH, *sWL;
  const float *stb;
  const u16 *ssH, *ssL;        // [S][B][H] planes (pos0 = h0; all pos for attend)
  const u16 *projbf;
  const float *attv;
  u16 *hAH, *hAL;
  const int *ids;
};

__global__ __launch_bounds__(256, 1)
void dec_mono(DecMP P) {
  __shared__ __align__(16) u16 hPl[2][4096];
  __shared__ __align__(16) u16 cPl[2][4096];
  __shared__ float hF[2048];
  __shared__ float pS[2048];
  __shared__ int ids_l[256];
  const int tid = threadIdx.x;
  const int lane = tid & 63, wv = tid >> 6;
  const int fr = lane & 15, kq = lane >> 4;
  const int jb = wv * 64;
  const int r0 = blockIdx.x * 8;

  {
    us8 z8 = {0,0,0,0,0,0,0,0};
    us8* pb = (us8*)&hPl[0][0];
    #pragma unroll
    for (int i = 0; i < 4; i++) pb[i * 256 + tid] = z8;    // hPl 1024 us8
    us8* cb = (us8*)&cPl[0][0];
    #pragma unroll
    for (int i = 0; i < 4; i++) cb[i * 256 + tid] = z8;    // cPl 1024 us8
  }
  ids_l[tid] = P.ids[(r0 + (tid >> 5)) * T_ + (tid & 31)];
  __syncthreads();
  // load h0 = ss[0] rows
  {
    int row = tid >> 5;          // 0..7
    int k = (tid & 31) * 8;
    size_t go = ((size_t)(r0 + row)) * 256 + k;   // pos 0
    us8 hv = *(const us8*)(P.ssH + go);
    us8 lv = *(const us8*)(P.ssL + go);
    int sl = row * 256 + ((((k >> 3) ^ (row & 7))) << 3);
    *(us8*)&hPl[0][sl] = hv;
    *(us8*)&hPl[1][sl] = lv;
    #pragma unroll
    for (int e = 0; e < 8; e++) hF[row * 256 + k + e] = bf2f(hv[e]) + bf2f(lv[e]);
  }

  float bz[4], br_[4], bxc[4], bhc[4], stbv[4];
  #pragma unroll
  for (int nt = 0; nt < 4; nt++) {
    int j = jb + nt * 16 + fr;
    bz[nt]  = P.bias[j] + P.bias[G3 + j];
    br_[nt] = P.bias[256 + j] + P.bias[G3 + 256 + j];
    bxc[nt] = P.bias[512 + j];
    bhc[nt] = P.bias[G3 + 512 + j];
    stbv[nt] = P.stb[j];
  }
  float vq[4];
  #pragma unroll
  for (int q = 0; q < 4; q++) vq[q] = P.attv[q * 64 + lane];
  __syncthreads();

  auto lp_attend = [&]() {
    // LP: p = h @ att_st_W + b  (MFMA, 3-pass)
    f32x4 pa[4];
    #pragma unroll
    for (int nt = 0; nt < 4; nt++) pa[nt] = (f32x4){0.f,0.f,0.f,0.f};
    #pragma unroll
    for (int i = 0; i < 8; i++) {
      int slot = (((i * 4 + kq) ^ (fr & 7)) << 3);
      short8 ah = *(const short8*)&hPl[0][fr * 256 + slot];
      short8 al = *(const short8*)&hPl[1][fr * 256 + slot];
      #pragma unroll
      for (int nt = 0; nt < 4; nt++) {
        size_t ro = (size_t)(jb + nt * 16 + fr) * 256 + i * 32 + kq * 8;
        short8 bh = *(const short8*)(P.sWH + ro);
        short8 bl = *(const short8*)(P.sWL + ro);
        pa[nt] = MFMA16(ah, bh, pa[nt], 0, 0, 0);
        pa[nt] = MFMA16(ah, bl, pa[nt], 0, 0, 0);
        pa[nt] = MFMA16(al, bh, pa[nt], 0, 0, 0);
      }
    }
    if (kq < 2) {
      #pragma unroll
      for (int rr = 0; rr < 4; rr++) {
        int row = kq * 4 + rr;
        #pragma unroll
        for (int nt = 0; nt < 4; nt++) {
          int j = jb + nt * 16 + fr;
          pS[row * 256 + j] = pa[nt][rr] + stbv[nt];
        }
      }
    }
    __syncthreads();
    // attend: wave handles rows 2wv, 2wv+1
    #pragma unroll 1
    for (int u = 0; u < 2; u++) {
      int row = wv * 2 + u;
      int gb = r0 + row;
      float pq[4];
      #pragma unroll
      for (int q = 0; q < 4; q++) pq[q] = pS[row * 256 + q * 64 + lane];
      float sc[S_];
      #pragma unroll
      for (int s2 = 0; s2 < S_; s2++) {
        const u16* pr = P.projbf + ((size_t)s2 * B_ + gb) * 256;
        float part = 0.f;
        #pragma unroll
        for (int q = 0; q < 4; q++)
          part += tanhf(bf2f(pr[q * 64 + lane]) + pq[q]) * vq[q];
        #pragma unroll
        for (int off = 32; off; off >>= 1)
          part += __shfl_xor(part, off);
        sc[s2] = part;   // butterfly: all lanes hold the sum
      }
      float m = -1e30f;
      #pragma unroll
      for (int s2 = 0; s2 < S_; s2++) m = fmaxf(m, sc[s2]);
      float den = 0.f;
      #pragma unroll
      for (int s2 = 0; s2 < S_; s2++) { sc[s2] = expf(sc[s2] - m); den += sc[s2]; }
      float inv = 1.f / den;
      float cacc[4] = {0.f, 0.f, 0.f, 0.f};
      #pragma unroll
      for (int s2 = 0; s2 < S_; s2++) {
        float w = sc[s2] * inv;
        const u16* sp = P.ssH + ((size_t)s2 * B_ + gb) * 256;
        #pragma unroll
        for (int q = 0; q < 4; q++)
          cacc[q] = fmaf(w, bf2f(sp[q * 64 + lane]), cacc[q]);
      }
      #pragma unroll
      for (int q = 0; q < 4; q++) {
        int j = q * 64 + lane;
        u16 hi = f2bf(cacc[q]);
        int ps = psl(row, j);
        cPl[0][ps] = hi;
        cPl[1][ps] = f2bf(cacc[q] - bf2f(hi));
      }
    }
  };

  lp_attend();          // ctx_init from h0
  __syncthreads();

  for (int t = 0; t < T_; t++) {
    f32x4 acc[4][4];
    #pragma unroll
    for (int a = 0; a < 4; a++)
      #pragma unroll
      for (int nt = 0; nt < 4; nt++) acc[a][nt] = (f32x4){0.f,0.f,0.f,0.f};

    #pragma unroll
    for (int i = 0; i < 16; i++) {
      const u16* BH = (i < 8) ? P.UH : P.CH;
      const u16* BL = (i < 8) ? P.UL : P.CL;
      const u16* a0p = (i < 8) ? hPl[0] : cPl[0];
      const u16* a1p = (i < 8) ? hPl[1] : cPl[1];
      int ii = i & 7;
      int slot = (((ii * 4 + kq) ^ (fr & 7)) << 3);
      short8 ah = *(const short8*)&a0p[fr * 256 + slot];
      short8 al = *(const short8*)&a1p[fr * 256 + slot];
      int ci = (i < 8) ? 2 : 3;
      #pragma unroll
      for (int st = 0; st < 3; st++) {
        int ai = (st < 2) ? st : ci;
        #pragma unroll
        for (int nt = 0; nt < 4; nt++) {
          size_t ro = (size_t)(st * 256 + jb + nt * 16 + fr) * 256 + ii * 32 + kq * 8;
          short8 bh = *(const short8*)(BH + ro);
          short8 bl = *(const short8*)(BL + ro);
          acc[ai][nt] = MFMA16(ah, bh, acc[ai][nt], 0, 0, 0);
          acc[ai][nt] = MFMA16(ah, bl, acc[ai][nt], 0, 0, 0);
          acc[ai][nt] = MFMA16(al, bh, acc[ai][nt], 0, 0, 0);
        }
      }
    }
    __syncthreads();
    if (kq < 2) {
      #pragma unroll
      for (int rr = 0; rr < 4; rr++) {
        int row = kq * 4 + rr;
        int gb = r0 + row;
        int id = (t == 0) ? BOW_ : ids_l[row * 32 + t - 1];
        const float* T = P.gxT + (size_t)id * G3;
        #pragma unroll
        for (int nt = 0; nt < 4; nt++) {
          int j = jb + nt * 16 + fr;
          float z = sigm(acc[0][nt][rr] + T[j] + bz[nt]);
          float r = sigm(acc[1][nt][rr] + T[256 + j] + br_[nt]);
          float c = tanhf(T[512 + j] + bxc[nt] + acc[3][nt][rr] + r * (acc[2][nt][rr] + bhc[nt]));
          float hp = hF[row * 256 + j];
          float hn = z * hp + (1.f - z) * c;
          hF[row * 256 + j] = hn;
          u16 hi = f2bf(hn);
          u16 lo = f2bf(hn - bf2f(hi));
          int ps = psl(row, j);
          hPl[0][ps] = hi; hPl[1][ps] = lo;
          size_t o = ((size_t)t * B_ + gb) * 256 + j;
          P.hAH[o] = hi; P.hAL[o] = lo;
        }
      }
    }
    __syncthreads();
    if (t < T_ - 1) {
      lp_attend();
      __syncthreads();
    }
  }
}

// ---------------- host ----------------
extern "C" void kernel_launch(void* const* d_in, const int* in_sizes, int n_in,
                              void* d_out, int out_size, void* d_ws, size_t ws_size,
                              hipStream_t stream) {
  const float* src_emb   = (const float*)d_in[0];
  const float* tgt_emb   = (const float*)d_in[1];
  const float* enc_f_W   = (const float*)d_in[2];
  const float* enc_f_U   = (const float*)d_in[3];
  const float* enc_f_b   = (const float*)d_in[4];
  const float* enc_b_W   = (const float*)d_in[5];
  const float* enc_b_U   = (const float*)d_in[6];
  const float* enc_b_b   = (const float*)d_in[7];
  const float* dec_W     = (const float*)d_in[8];
  const float* dec_U     = (const float*)d_in[9];
  const float* dec_b     = (const float*)d_in[10];
  const float* out_W     = (const float*)d_in[11];
  const float* out_b     = (const float*)d_in[12];
  const float* att_src_W = (const float*)d_in[13];
  const float* att_src_b = (const float*)d_in[14];
  const float* att_st_W  = (const float*)d_in[15];
  const float* att_st_b  = (const float*)d_in[16];
  const float* att_v     = (const float*)d_in[17];
  const int* source_ids  = (const int*)d_in[19];
  const int* target_ids  = (const int*)d_in[20];
  float* out = (float*)d_out;

  char* base = (char*)d_ws;
  size_t off = 0;
  auto allocB = [&](size_t bytes) { void* p = base + off; off = (off + bytes + 255) & ~255UL; return p; };
  const size_t BH = (size_t)B_ * H_;

  u16* ssH    = (u16*)allocB((size_t)S_ * BH * 2);
  u16* ssL    = (u16*)allocB((size_t)S_ * BH * 2);
  u16* projbf = (u16*)allocB((size_t)S_ * BH * 2);
  u16* hAllH  = (u16*)allocB((size_t)T_ * BH * 2);
  u16* hAllL  = (u16*)allocB((size_t)T_ * BH * 2);

  auto planes2 = [&](size_t n, u16*& h, u16*& l) { h = (u16*)allocB(n * 2); l = (u16*)allocB(n * 2); };
  u16 *UtFh,*UtFl,*UtBh,*UtBl,*WtFh,*WtFl,*WtBh,*WtBl;
  u16 *dUth,*dUtl,*dWcth,*dWctl,*dWxth,*dWxtl;
  u16 *oWth,*oWtl,*aStth,*aSttl,*aSrth,*aSrtl;
  u16 *sEh,*sEl,*tEh,*tEl;
  planes2((size_t)G3*H_, UtFh, UtFl);   planes2((size_t)G3*H_, UtBh, UtBl);
  planes2((size_t)G3*D_, WtFh, WtFl);   planes2((size_t)G3*D_, WtBh, WtBl);
  planes2((size_t)G3*H_, dUth, dUtl);   planes2((size_t)G3*H_, dWcth, dWctl);
  planes2((size_t)G3*D_, dWxth, dWxtl);
  planes2((size_t)H_*VT_, oWth, oWtl);
  planes2((size_t)H_*H_, aSrth, aSrtl);
  planes2((size_t)H_*H_, aStth, aSttl);
  planes2((size_t)VT_*D_, sEh, sEl);    planes2((size_t)VT_*D_, tEh, tEl);
  float* Tf = (float*)allocB((size_t)VT_ * G3 * 4);
  float* Tb = (float*)allocB((size_t)VT_ * G3 * 4);
  float* Td = (float*)allocB((size_t)VT_ * G3 * 4);

  TPack P;
  P.m[0] = { enc_f_U,          UtFh, UtFl, 256, 768, 0   };
  P.m[1] = { enc_b_U,          UtBh, UtBl, 256, 768, 48  };
  P.m[2] = { dec_U,            dUth, dUtl, 256, 768, 96  };
  P.m[3] = { dec_W + 128 * G3, dWcth, dWctl, 256, 768, 144 };
  P.m[4] = { enc_f_W,          WtFh, WtFl, 128, 768, 192 };
  P.m[5] = { enc_b_W,          WtBh, WtBl, 128, 768, 216 };
  P.m[6] = { dec_W,            dWxth, dWxtl, 128, 768, 240 };
  P.m[7] = { out_W,            oWth, oWtl, 256, 256, 264 };
  P.m[8] = { att_src_W,        aSrth, aSrtl, 256, 256, 280 };
  P.m[9] = { att_st_W,         aStth, aSttl, 256, 256, 296 };
  wsplit_t<<<312, 256, 0, stream>>>(P);
  esplit<<<(2 * VT_ * D_ + 255) / 256, 256, 0, stream>>>(src_emb, tgt_emb, sEh, sEl, tEh, tEl, VT_ * D_);

  // gx tables: emb @ W (split-bf16 3-pass, f32 out)
  {
    PLeg tf = { sEh, sEl, D_, WtFh, WtFl, D_, nullptr, Tf, G3, 0, VT_, G3, D_ };
    PLeg tb = { sEh, sEl, D_, WtBh, WtBl, D_, nullptr, Tb, G3, 0, VT_, G3, D_ };
    gemm_pl<<<dim3(6, 2, 2), 256, 0, stream>>>(tf, tb);
    PLeg td = { tEh, tEl, D_, dWxth, dWxtl, D_, nullptr, Td, G3, 0, VT_, G3, D_ };
    gemm_pl<<<dim3(6, 2, 1), 256, 0, stream>>>(td, td);
  }

  // ---- monolithic encoder: 1 launch ----
  {
    EncMP Pe;
    Pe.UH0 = UtFh; Pe.UL0 = UtFl; Pe.UH1 = UtBh; Pe.UL1 = UtBl;
    Pe.gxT0 = Tf; Pe.gxT1 = Tb;
    Pe.bias0 = enc_f_b; Pe.bias1 = enc_b_b;
    Pe.ssH = ssH; Pe.ssL = ssL;
    Pe.ids = source_ids;
    enc_mono<<<256, 256, 0, stream>>>(Pe);
  }

  // ---- proj (bf16) ----
  {
    PLeg proj = { ssH, ssL, H_, aSrth, aSrtl, H_, att_src_b, projbf, H_, 1, S_ * B_, H_, H_ };
    gemm_pl<<<dim3(2, 512, 1), 256, 0, stream>>>(proj, proj);
  }

  // ---- monolithic decoder: 1 launch ----
  {
    DecMP Pd;
    Pd.UH = dUth; Pd.UL = dUtl; Pd.CH = dWcth; Pd.CL = dWctl;
    Pd.gxT = Td;
    Pd.bias = dec_b;
    Pd.sWH = aStth; Pd.sWL = aSttl;
    Pd.stb = att_st_b;
    Pd.ssH = ssH; Pd.ssL = ssL;
    Pd.projbf = projbf;
    Pd.attv = att_v;
    Pd.hAH = hAllH; Pd.hAL = hAllL;
    Pd.ids = target_ids;
    dec_mono<<<256, 256, 0, stream>>>(Pd);
  }

  // ---- batched logits ----
  {
    PLeg LO = { hAllH, hAllL, H_, oWth, oWtl, H_, out_b, out, 0, 2, T_ * B_, VT_, H_ };
    gemm_pl<<<dim3(2, 512, 1), 256, 0, stream>>>(LO, LO);
  }
}

// Round 11
// 4293.747 us; speedup vs baseline: 2.8493x; 2.8493x over previous
//
#include <hip/hip_runtime.h>
#include <math.h>

#define B_  2048
#define S_  32
#define T_  32
#define D_  128
#define H_  256
#define G3  768
#define VT_ 256
#define BOW_ 1

typedef __attribute__((ext_vector_type(8))) short short8;
typedef __attribute__((ext_vector_type(4))) float f32x4;
typedef __attribute__((ext_vector_type(8))) unsigned short us8;
typedef unsigned short u16;

#define MFMA16 __builtin_amdgcn_mfma_f32_16x16x32_bf16

__device__ inline u16 f2bf(float x) {
  union { float f; unsigned u; } v; v.f = x;
  unsigned r = v.u + 0x7FFFu + ((v.u >> 16) & 1u);
  return (u16)(r >> 16);
}
__device__ inline float bf2f(u16 b) {
  union { unsigned u; float f; } v; v.u = ((unsigned)b) << 16; return v.f;
}
__device__ inline int swz(int r) { return ((r ^ (r >> 3)) & 7) << 3; }
__device__ inline float sigm(float x) { return 1.f / (1.f + expf(-x)); }

// ---------------- weight transpose + split ----------------
struct TMat { const float* src; u16* dhi; u16* dlo; int R; int C; int tile0; };
struct TPack { TMat m[10]; };

__global__ __launch_bounds__(256)
void wsplit_t(TPack P) {
  int bx = blockIdx.x;
  TMat M = P.m[0];
  #pragma unroll
  for (int i = 1; i < 10; i++) if (bx >= P.m[i].tile0) M = P.m[i];
  int ti = bx - M.tile0;
  int tilesR = M.R >> 6;
  int rt = ti % tilesR, ct = ti / tilesR;
  int r0 = rt * 64, c0 = ct * 64;
  __shared__ float ts[64][65];
  int tid = threadIdx.x;
  int cx = tid & 63, ry = tid >> 6;
  #pragma unroll
  for (int i = 0; i < 16; i++) {
    int r = ry * 16 + i;
    ts[r][cx] = M.src[(size_t)(r0 + r) * M.C + c0 + cx];
  }
  __syncthreads();
  int rx = tid & 63, cy = tid >> 6;
  #pragma unroll
  for (int i = 0; i < 16; i++) {
    int cc = cy * 16 + i;
    float v = ts[rx][cc];
    u16 hi = f2bf(v);
    size_t o = (size_t)(c0 + cc) * M.R + r0 + rx;
    M.dhi[o] = hi;
    M.dlo[o] = f2bf(v - bf2f(hi));
  }
}

__global__ __launch_bounds__(256)
void esplit(const float* a, const float* b, u16* ah, u16* al, u16* bh, u16* bl, int n) {
  int i = blockIdx.x * 256 + threadIdx.x;
  if (i >= 2 * n) return;
  const float* s = (i < n) ? a : b;
  u16* dh = (i < n) ? ah : bh;
  u16* dl = (i < n) ? al : bl;
  int j = (i < n) ? i : i - n;
  float v = s[j];
  u16 hi = f2bf(v);
  dh[j] = hi; dl[j] = f2bf(v - bf2f(hi));
}

// ---------------- plane GEMM ----------------
struct PLeg {
  const u16* Ahi; const u16* Alo; int lda;
  const u16* Bthi; const u16* Btlo; int ldb;
  const float* bias; void* C; int ldc; int cmode;  // 0=f32, 1=bf16, 2=logits-layout
  int M, N, K;
};

__global__ __launch_bounds__(256)
void gemm_pl(PLeg l0, PLeg l1) {
  PLeg L = blockIdx.z ? l1 : l0;
  int n0 = blockIdx.x * 128; if (n0 >= L.N) return;
  int m0 = blockIdx.y * 128; if (m0 >= L.M) return;
  __shared__ u16 As[128 * 64];
  __shared__ u16 Bs[128 * 64];
  int tid = threadIdx.x;
  int lane = tid & 63, wv = tid >> 6;
  int wr = (wv >> 1) * 64, wc = (wv & 1) * 64;
  int fr = lane & 15, fk = (lane >> 4) * 8;
  f32x4 acc[4][4];
  #pragma unroll
  for (int m = 0; m < 4; m++)
    #pragma unroll
    for (int n = 0; n < 4; n++) acc[m][n] = (f32x4){0.f, 0.f, 0.f, 0.f};

  int s_row = tid >> 1, s_part = tid & 1;

  for (int k0 = 0; k0 < L.K; k0 += 32) {
    if (k0) __syncthreads();
    int swA = swz(s_row);
    {
      const u16* src = (s_part ? L.Alo : L.Ahi) + (size_t)(m0 + s_row) * L.lda + k0;
      #pragma unroll
      for (int q = 0; q < 4; q++)
        *(us8*)&As[(s_row * 64 + s_part * 32 + q * 8) ^ swA] = *(const us8*)(src + q * 8);
    }
    {
      const u16* src = (s_part ? L.Btlo : L.Bthi) + (size_t)(n0 + s_row) * L.ldb + k0;
      #pragma unroll
      for (int q = 0; q < 4; q++)
        *(us8*)&Bs[(s_row * 64 + s_part * 32 + q * 8) ^ swA] = *(const us8*)(src + q * 8);
    }
    __syncthreads();
    short8 bhi[4], blo[4];
    #pragma unroll
    for (int n = 0; n < 4; n++) {
      int cc = wc + n * 16 + fr; int sw = swz(cc);
      bhi[n] = *(const short8*)&Bs[(cc * 64 + fk) ^ sw];
      blo[n] = *(const short8*)&Bs[(cc * 64 + 32 + fk) ^ sw];
    }
    #pragma unroll
    for (int m = 0; m < 4; m++) {
      int r = wr + m * 16 + fr; int sw = swz(r);
      short8 ahi = *(const short8*)&As[(r * 64 + fk) ^ sw];
      short8 alo = *(const short8*)&As[(r * 64 + 32 + fk) ^ sw];
      #pragma unroll
      for (int n = 0; n < 4; n++) {
        acc[m][n] = MFMA16(ahi, bhi[n], acc[m][n], 0, 0, 0);
        acc[m][n] = MFMA16(ahi, blo[n], acc[m][n], 0, 0, 0);
        acc[m][n] = MFMA16(alo, bhi[n], acc[m][n], 0, 0, 0);
      }
    }
  }
  int rbase = (lane >> 4) * 4;
  #pragma unroll
  for (int m = 0; m < 4; m++)
    #pragma unroll
    for (int rr = 0; rr < 4; rr++) {
      int row = m0 + wr + m * 16 + rbase + rr;
      #pragma unroll
      for (int n = 0; n < 4; n++) {
        int col = n0 + wc + n * 16 + fr;
        float v = acc[m][n][rr];
        if (L.bias) v += L.bias[col];
        if (L.cmode == 0)      ((float*)L.C)[(size_t)row * L.ldc + col] = v;
        else if (L.cmode == 1) ((u16*)L.C)[(size_t)row * L.ldc + col] = f2bf(v);
        else {
          size_t o = (((size_t)(row & (B_ - 1))) * T_ + (row >> 11)) * VT_ + col;
          ((float*)L.C)[o] = v;
        }
      }
    }
}

// ---------------- encoder step (r7 gru_step<0>, verbatim semantics) ----------------
struct EncD {
  const u16 *a0H, *a0L;
  const u16 *b0H, *b0L;
  const float *gxT;
  const float *bias0, *bias1;
  const float *hold;
  float *hnew;
  u16 *hh, *hl;
  u16 *ssH, *ssL;
  const int *ids;
  int ssmode;      // 1 store, 2 add
  int sidx, rev;
};

__global__ __launch_bounds__(256)
void enc_step(EncD d0, EncD d1) {
  EncD D = blockIdx.z ? d1 : d0;
  __shared__ __align__(16) u16 As[2 * 32 * 256];

  int m0 = blockIdx.y * 32;
  int tid = threadIdx.x;
  int lane = tid & 63, wv = tid >> 6;
  int fr = lane & 15, kq = lane >> 4;
  int jn = blockIdx.x * 64 + wv * 16 + fr;

  #pragma unroll
  for (int i = 0; i < 8; i++) {
    int s = tid + i * 256;
    int p = s >> 10;
    int rem = s & 1023;
    int row = rem >> 5;
    const u16* src = (p ? D.a0L : D.a0H) + (size_t)(m0 + row) * 256 + (rem & 31) * 8;
    *(us8*)&As[(s ^ (row & 7)) * 8] = *(const us8*)src;
  }
  __syncthreads();

  f32x4 acc[3];
  #pragma unroll
  for (int a = 0; a < 3; a++) acc[a] = (f32x4){0.f,0.f,0.f,0.f};
  f32x4 acc2[3];
  #pragma unroll
  for (int a = 0; a < 3; a++) acc2[a] = (f32x4){0.f,0.f,0.f,0.f};

  #pragma unroll
  for (int i = 0; i < 8; i++) {
    short8 ah[2], al[2];
    #pragma unroll
    for (int mf = 0; mf < 2; mf++) {
      int rp = mf * 16 + fr;
      int kb = i * 4 + kq;
      ah[mf] = *(const short8*)&As[((rp * 32 + kb) ^ (fr & 7)) * 8];
      al[mf] = *(const short8*)&As[((1024 + rp * 32 + kb) ^ (fr & 7)) * 8];
    }
    #pragma unroll
    for (int st = 0; st < 3; st++) {
      size_t ro = (size_t)(st * 256 + jn) * 256 + i * 32 + kq * 8;
      short8 bh = *(const short8*)(D.b0H + ro);
      short8 bl = *(const short8*)(D.b0L + ro);
      acc[st]  = MFMA16(ah[0], bh, acc[st], 0, 0, 0);
      acc[st]  = MFMA16(ah[0], bl, acc[st], 0, 0, 0);
      acc[st]  = MFMA16(al[0], bh, acc[st], 0, 0, 0);
      acc2[st] = MFMA16(ah[1], bh, acc2[st], 0, 0, 0);
      acc2[st] = MFMA16(ah[1], bl, acc2[st], 0, 0, 0);
      acc2[st] = MFMA16(al[1], bh, acc2[st], 0, 0, 0);
    }
  }

  float b0z = D.bias0[jn] + D.bias1[jn];
  float b0r = D.bias0[256 + jn] + D.bias1[256 + jn];
  float bxc = D.bias0[512 + jn];
  float bhc = D.bias1[512 + jn];
  int rbase = kq * 4;
  #pragma unroll
  for (int mf = 0; mf < 2; mf++)
    #pragma unroll
    for (int rr = 0; rr < 4; rr++) {
      int b = m0 + mf * 16 + rbase + rr;
      size_t o = (size_t)b * H_ + jn;
      int id = D.ids[b * S_ + (D.rev ? (S_ - 1 - D.sidx) : D.sidx)];
      const float* T = D.gxT + (size_t)id * G3;
      float az  = mf ? acc2[0][rr] : acc[0][rr];
      float ar  = mf ? acc2[1][rr] : acc[1][rr];
      float ahc = mf ? acc2[2][rr] : acc[2][rr];
      float z = sigm(az + T[jn] + b0z);
      float r = sigm(ar + T[256 + jn] + b0r);
      float c = tanhf(T[512 + jn] + bxc + r * (ahc + bhc));
      float hn = z * D.hold[o] + (1.f - z) * c;
      D.hnew[o] = hn;
      u16 hi = f2bf(hn);
      u16 lo = f2bf(hn - bf2f(hi));
      D.hh[o] = hi; D.hl[o] = lo;
      if (D.ssmode == 1) {
        D.ssH[o] = hi; D.ssL[o] = lo;
      } else {
        float v = bf2f(D.ssH[o]) + bf2f(D.ssL[o]) + hn;
        u16 vh = f2bf(v);
        D.ssH[o] = vh; D.ssL[o] = f2bf(v - bf2f(vh));
      }
    }
}

// ---------------- initial attention (r7 attend_k verbatim) ----------------
__global__ __launch_bounds__(256)
void attend_k(const u16* __restrict__ projbf, const u16* __restrict__ ssH,
              const float* __restrict__ p, const float* __restrict__ att_v,
              u16* __restrict__ ctxh, u16* __restrict__ ctxl) {
  int b = blockIdx.x;
  int tid = threadIdx.x;
  int lane = tid & 63;
  int wv = tid >> 6;
  __shared__ float e_s[S_];
  __shared__ float w_s[S_];
  float pq[4], vq[4];
  #pragma unroll
  for (int q = 0; q < 4; q++) {
    pq[q] = p[(size_t)b * H_ + q * 64 + lane];
    vq[q] = att_v[q * 64 + lane];
  }
  float pv[8][4];
  #pragma unroll
  for (int i = 0; i < 8; i++) {
    const u16* pr = projbf + ((size_t)(wv * 8 + i) * B_ + b) * H_;
    #pragma unroll
    for (int q = 0; q < 4; q++) pv[i][q] = bf2f(pr[q * 64 + lane]);
  }
  u16 sv[S_];
  #pragma unroll
  for (int s = 0; s < S_; s++) sv[s] = ssH[((size_t)s * B_ + b) * H_ + tid];

  #pragma unroll
  for (int i = 0; i < 8; i++) {
    float part = 0.f;
    #pragma unroll
    for (int q = 0; q < 4; q++)
      part += tanhf(pv[i][q] + pq[q]) * vq[q];
    #pragma unroll
    for (int off = 32; off; off >>= 1)
      part += __shfl_xor(part, off);
    if (lane == 0) e_s[wv * 8 + i] = part;
  }
  __syncthreads();
  float m = -1e30f;
  #pragma unroll
  for (int s = 0; s < S_; s++) m = fmaxf(m, e_s[s]);
  float den = 0.f;
  #pragma unroll
  for (int s = 0; s < S_; s++) den += expf(e_s[s] - m);
  if (tid < S_) w_s[tid] = expf(e_s[tid] - m) / den;
  __syncthreads();
  float acc = 0.f;
  #pragma unroll
  for (int s = 0; s < S_; s++)
    acc = fmaf(w_s[s], bf2f(sv[s]), acc);
  u16 hi = f2bf(acc);
  size_t o = (size_t)b * H_ + tid;
  ctxh[o] = hi; ctxl[o] = f2bf(acc - bf2f(hi));
}

// ================= fused decoder step: gru + LP + attend, 1 launch =================
struct DSP {
  const u16 *hPH, *hPL;        // h_{t-1} planes
  const float *hPF;            // h_{t-1} f32 (null at t=0 -> plane sum)
  float *hFo;                  // h_t f32 out
  const u16 *UH, *UL, *CH, *CL;
  const u16 *sWH, *sWL;
  const float *gxT, *bias, *stb, *attv;
  const u16 *ssH;              // attend V + (pos0 unused here)
  const u16 *projbf;
  u16 *hAH, *hAL;              // h_t planes out (hAll + t*BH)
  u16 *ctxH, *ctxL;            // in/out (block-local rows)
  const int *ids;
  int t, last;
};

__global__ __launch_bounds__(512, 1)
void dec_step(DSP P) {
  __shared__ __align__(16) u16 AH[16 * 512];   // 16 KB  (k-concat [h|ctx], rows 8-15 zero)
  __shared__ __align__(16) u16 AL[16 * 512];   // 16 KB
  __shared__ float pS[8 * 256];                // 8 KB
  const int tid = threadIdx.x;
  const int lane = tid & 63, w = tid >> 6;     // 8 waves
  const int fr = lane & 15, kq = lane >> 4;
  const int r0 = blockIdx.x * 8;

  // ---- stage A panel: rows 0-7 = [h_{t-1} | ctx], rows 8-15 = 0 ----
  #pragma unroll
  for (int i = 0; i < 4; i++) {
    int s = tid + i * 512;             // 0..2047
    int p = s >> 10;
    int rem = s & 1023;
    int row = rem >> 6;
    int k8 = rem & 63;
    us8 v = {0,0,0,0,0,0,0,0};
    if (row < 8) {
      const u16* src = (k8 < 32)
        ? (p ? P.hPL : P.hPH) + (size_t)(r0 + row) * 256 + k8 * 8
        : (p ? P.ctxL : P.ctxH) + (size_t)(r0 + row) * 256 + (k8 - 32) * 8;
      v = *(const us8*)src;
    }
    int slot = row * 64 + (k8 ^ (row & 7));
    if (p) *(us8*)&AL[slot * 8] = v;
    else   *(us8*)&AH[slot * 8] = v;
  }
  __syncthreads();

  // ---- gates: wave w owns j-tiles {2w, 2w+1}; acc: 0=z 1=r 2=hc 3=xc ----
  f32x4 acc[4][2];
  #pragma unroll
  for (int a = 0; a < 4; a++)
    #pragma unroll
    for (int q = 0; q < 2; q++) acc[a][q] = (f32x4){0.f,0.f,0.f,0.f};

  #pragma unroll
  for (int i = 0; i < 16; i++) {
    int slot = fr * 64 + ((i * 4 + kq) ^ (fr & 7));
    short8 ah = *(const short8*)&AH[slot * 8];
    short8 al = *(const short8*)&AL[slot * 8];
    const u16* BH = (i < 8) ? P.UH : P.CH;
    const u16* BL = (i < 8) ? P.UL : P.CL;
    int bk = (i & 7) * 32 + kq * 8;
    int ci = (i < 8) ? 2 : 3;
    #pragma unroll
    for (int st = 0; st < 3; st++) {
      int ai = (st < 2) ? st : ci;
      #pragma unroll
      for (int q = 0; q < 2; q++) {
        size_t ro = (size_t)(st * 256 + (2 * w + q) * 16 + fr) * 256 + bk;
        short8 bh = *(const short8*)(BH + ro);
        short8 bl = *(const short8*)(BL + ro);
        acc[ai][q] = MFMA16(ah, bh, acc[ai][q], 0, 0, 0);
        acc[ai][q] = MFMA16(ah, bl, acc[ai][q], 0, 0, 0);
        acc[ai][q] = MFMA16(al, bh, acc[ai][q], 0, 0, 0);
      }
    }
  }
  __syncthreads();   // all A-reads done before h-overwrite

  // ---- gate epilogue (lanes kq<2 hold valid rows 0..7) ----
  if (kq < 2) {
    #pragma unroll
    for (int rr = 0; rr < 4; rr++) {
      int row = kq * 4 + rr;
      int gb = r0 + row;
      int id = (P.t == 0) ? BOW_ : P.ids[gb * T_ + P.t - 1];
      const float* T = P.gxT + (size_t)id * G3;
      #pragma unroll
      for (int q = 0; q < 2; q++) {
        int j = (2 * w + q) * 16 + fr;
        size_t o = (size_t)gb * H_ + j;
        float z = sigm(acc[0][q][rr] + T[j] + P.bias[j] + P.bias[G3 + j]);
        float r = sigm(acc[1][q][rr] + T[256 + j] + P.bias[256 + j] + P.bias[G3 + 256 + j]);
        float c = tanhf(T[512 + j] + P.bias[512 + j] + acc[3][q][rr]
                        + r * (acc[2][q][rr] + P.bias[G3 + 512 + j]));
        float hp;
        if (P.hPF) hp = P.hPF[o];
        else {
          int sl = row * 64 + ((j >> 3) ^ (row & 7));
          hp = bf2f(AH[sl * 8 + (j & 7)]) + bf2f(AL[sl * 8 + (j & 7)]);
        }
        float hn = z * hp + (1.f - z) * c;
        P.hFo[o] = hn;
        u16 hi = f2bf(hn);
        u16 lo = f2bf(hn - bf2f(hi));
        P.hAH[o] = hi; P.hAL[o] = lo;
        int sl = row * 64 + ((j >> 3) ^ (row & 7));
        AH[sl * 8 + (j & 7)] = hi;
        AL[sl * 8 + (j & 7)] = lo;
      }
    }
  }
  if (P.last) return;
  __syncthreads();

  // ---- LP: p = h_t @ att_st_W + b (wave w owns j-tiles {2w, 2w+1}) ----
  f32x4 pa[2];
  #pragma unroll
  for (int q = 0; q < 2; q++) pa[q] = (f32x4){0.f,0.f,0.f,0.f};
  #pragma unroll
  for (int i = 0; i < 8; i++) {
    int slot = fr * 64 + ((i * 4 + kq) ^ (fr & 7));
    short8 ah = *(const short8*)&AH[slot * 8];
    short8 al = *(const short8*)&AL[slot * 8];
    #pragma unroll
    for (int q = 0; q < 2; q++) {
      size_t ro = (size_t)((2 * w + q) * 16 + fr) * 256 + i * 32 + kq * 8;
      short8 bh = *(const short8*)(P.sWH + ro);
      short8 bl = *(const short8*)(P.sWL + ro);
      pa[q] = MFMA16(ah, bh, pa[q], 0, 0, 0);
      pa[q] = MFMA16(ah, bl, pa[q], 0, 0, 0);
      pa[q] = MFMA16(al, bh, pa[q], 0, 0, 0);
    }
  }
  if (kq < 2) {
    #pragma unroll
    for (int rr = 0; rr < 4; rr++) {
      int row = kq * 4 + rr;
      #pragma unroll
      for (int q = 0; q < 2; q++) {
        int j = (2 * w + q) * 16 + fr;
        pS[row * 256 + j] = pa[q][rr] + P.stb[j];
      }
    }
  }
  __syncthreads();

  // ---- attend: wave w handles row w ----
  {
    int gb = r0 + w;
    float pq[4], vq[4];
    #pragma unroll
    for (int q = 0; q < 4; q++) {
      pq[q] = pS[w * 256 + q * 64 + lane];
      vq[q] = P.attv[q * 64 + lane];
    }
    float sc[S_];
    #pragma unroll 8
    for (int s2 = 0; s2 < S_; s2++) {
      const u16* pr = P.projbf + ((size_t)s2 * B_ + gb) * 256;
      float part = 0.f;
      #pragma unroll
      for (int q = 0; q < 4; q++)
        part += tanhf(bf2f(pr[q * 64 + lane]) + pq[q]) * vq[q];
      #pragma unroll
      for (int off = 32; off; off >>= 1)
        part += __shfl_xor(part, off);
      sc[s2] = part;
    }
    float m = -1e30f;
    #pragma unroll
    for (int s2 = 0; s2 < S_; s2++) m = fmaxf(m, sc[s2]);
    float den = 0.f;
    #pragma unroll
    for (int s2 = 0; s2 < S_; s2++) { sc[s2] = expf(sc[s2] - m); den += sc[s2]; }
    float inv = 1.f / den;
    float cacc[4] = {0.f, 0.f, 0.f, 0.f};
    #pragma unroll 8
    for (int s2 = 0; s2 < S_; s2++) {
      float wgt = sc[s2] * inv;
      const u16* sp = P.ssH + ((size_t)s2 * B_ + gb) * 256;
      #pragma unroll
      for (int q = 0; q < 4; q++)
        cacc[q] = fmaf(wgt, bf2f(sp[q * 64 + lane]), cacc[q]);
    }
    #pragma unroll
    for (int q = 0; q < 4; q++) {
      size_t o = (size_t)gb * H_ + q * 64 + lane;
      u16 hi = f2bf(cacc[q]);
      P.ctxH[o] = hi;
      P.ctxL[o] = f2bf(cacc[q] - bf2f(hi));
    }
  }
}

// ---------------- host ----------------
extern "C" void kernel_launch(void* const* d_in, const int* in_sizes, int n_in,
                              void* d_out, int out_size, void* d_ws, size_t ws_size,
                              hipStream_t stream) {
  const float* src_emb   = (const float*)d_in[0];
  const float* tgt_emb   = (const float*)d_in[1];
  const float* enc_f_W   = (const float*)d_in[2];
  const float* enc_f_U   = (const float*)d_in[3];
  const float* enc_f_b   = (const float*)d_in[4];
  const float* enc_b_W   = (const float*)d_in[5];
  const float* enc_b_U   = (const float*)d_in[6];
  const float* enc_b_b   = (const float*)d_in[7];
  const float* dec_W     = (const float*)d_in[8];
  const float* dec_U     = (const float*)d_in[9];
  const float* dec_b     = (const float*)d_in[10];
  const float* out_W     = (const float*)d_in[11];
  const float* out_b     = (const float*)d_in[12];
  const float* att_src_W = (const float*)d_in[13];
  const float* att_src_b = (const float*)d_in[14];
  const float* att_st_W  = (const float*)d_in[15];
  const float* att_st_b  = (const float*)d_in[16];
  const float* att_v     = (const float*)d_in[17];
  const int* source_ids  = (const int*)d_in[19];
  const int* target_ids  = (const int*)d_in[20];
  float* out = (float*)d_out;

  char* base = (char*)d_ws;
  size_t off = 0;
  auto allocB = [&](size_t bytes) { void* p = base + off; off = (off + bytes + 255) & ~255UL; return p; };
  const size_t BH = (size_t)B_ * H_;

  u16* ssH    = (u16*)allocB((size_t)S_ * BH * 2);
  u16* ssL    = (u16*)allocB((size_t)S_ * BH * 2);
  u16* projbf = (u16*)allocB((size_t)S_ * BH * 2);
  float* pbuf = (float*)allocB(BH * 4);
  u16* ctxh = (u16*)allocB(BH * 2);
  u16* ctxl = (u16*)allocB(BH * 2);

  float* encF0 = (float*)allocB(2 * BH * 4);
  u16*  encPl0 = (u16*)allocB(4 * BH * 2);
  float* encF1 = (float*)allocB(2 * BH * 4);
  u16*  encPl1 = (u16*)allocB(4 * BH * 2);
  float* encF[2][2]  = { { encF0, encF0 + BH }, { encF1, encF1 + BH } };
  u16*  encH[2][2]   = { { encPl0, encPl0 + 2 * BH }, { encPl1, encPl1 + 2 * BH } };
  u16*  encL[2][2]   = { { encPl0 + BH, encPl0 + 3 * BH }, { encPl1 + BH, encPl1 + 3 * BH } };

  float* hDecF[2] = { (float*)allocB(BH * 4), (float*)allocB(BH * 4) };
  u16* hAllH = (u16*)allocB((size_t)T_ * BH * 2);
  u16* hAllL = (u16*)allocB((size_t)T_ * BH * 2);

  auto planes2 = [&](size_t n, u16*& h, u16*& l) { h = (u16*)allocB(n * 2); l = (u16*)allocB(n * 2); };
  u16 *UtFh,*UtFl,*UtBh,*UtBl,*WtFh,*WtFl,*WtBh,*WtBl;
  u16 *dUth,*dUtl,*dWcth,*dWctl,*dWxth,*dWxtl;
  u16 *oWth,*oWtl,*aStth,*aSttl,*aSrth,*aSrtl;
  u16 *sEh,*sEl,*tEh,*tEl;
  planes2((size_t)G3*H_, UtFh, UtFl);   planes2((size_t)G3*H_, UtBh, UtBl);
  planes2((size_t)G3*D_, WtFh, WtFl);   planes2((size_t)G3*D_, WtBh, WtBl);
  planes2((size_t)G3*H_, dUth, dUtl);   planes2((size_t)G3*H_, dWcth, dWctl);
  planes2((size_t)G3*D_, dWxth, dWxtl);
  planes2((size_t)H_*VT_, oWth, oWtl);
  planes2((size_t)H_*H_, aSrth, aSrtl);
  planes2((size_t)H_*H_, aStth, aSttl);
  planes2((size_t)VT_*D_, sEh, sEl);    planes2((size_t)VT_*D_, tEh, tEl);
  float* Tf = (float*)allocB((size_t)VT_ * G3 * 4);
  float* Tb = (float*)allocB((size_t)VT_ * G3 * 4);
  float* Td = (float*)allocB((size_t)VT_ * G3 * 4);

  TPack P;
  P.m[0] = { enc_f_U,          UtFh, UtFl, 256, 768, 0   };
  P.m[1] = { enc_b_U,          UtBh, UtBl, 256, 768, 48  };
  P.m[2] = { dec_U,            dUth, dUtl, 256, 768, 96  };
  P.m[3] = { dec_W + 128 * G3, dWcth, dWctl, 256, 768, 144 };
  P.m[4] = { enc_f_W,          WtFh, WtFl, 128, 768, 192 };
  P.m[5] = { enc_b_W,          WtBh, WtBl, 128, 768, 216 };
  P.m[6] = { dec_W,            dWxth, dWxtl, 128, 768, 240 };
  P.m[7] = { out_W,            oWth, oWtl, 256, 256, 264 };
  P.m[8] = { att_src_W,        aSrth, aSrtl, 256, 256, 280 };
  P.m[9] = { att_st_W,         aStth, aSttl, 256, 256, 296 };
  wsplit_t<<<312, 256, 0, stream>>>(P);
  esplit<<<(2 * VT_ * D_ + 255) / 256, 256, 0, stream>>>(src_emb, tgt_emb, sEh, sEl, tEh, tEl, VT_ * D_);

  // gx tables
  {
    PLeg tf = { sEh, sEl, D_, WtFh, WtFl, D_, nullptr, Tf, G3, 0, VT_, G3, D_ };
    PLeg tb = { sEh, sEl, D_, WtBh, WtBl, D_, nullptr, Tb, G3, 0, VT_, G3, D_ };
    gemm_pl<<<dim3(6, 2, 2), 256, 0, stream>>>(tf, tb);
    PLeg td = { tEh, tEl, D_, dWxth, dWxtl, D_, nullptr, Td, G3, 0, VT_, G3, D_ };
    gemm_pl<<<dim3(6, 2, 1), 256, 0, stream>>>(td, td);
  }

  hipMemsetAsync(encF0, 0, 2 * BH * 4, stream);
  hipMemsetAsync(encPl0, 0, 4 * BH * 2, stream);

  // ---- encoder (r7 structure: 1 launch/step, z=2 dirs) ----
  for (int s = 0; s < S_; s++) {
    int p = s & 1;
    EncD dd[2];
    for (int d = 0; d < 2; d++) {
      EncD& D = dd[d];
      D.a0H = encH[p][d]; D.a0L = encL[p][d];
      D.b0H = d ? UtBh : UtFh; D.b0L = d ? UtBl : UtFl;
      D.gxT = d ? Tb : Tf;
      D.bias0 = d ? enc_b_b : enc_f_b;
      D.bias1 = (d ? enc_b_b : enc_f_b) + G3;
      D.hold = encF[p][d];
      D.hnew = encF[p ^ 1][d];
      D.hh = encH[p ^ 1][d]; D.hl = encL[p ^ 1][d];
      int pos = d ? (S_ - 1 - s) : s;
      D.ssH = ssH + (size_t)pos * BH; D.ssL = ssL + (size_t)pos * BH;
      D.ids = source_ids;
      D.ssmode = (s < S_ / 2) ? 1 : 2;
      D.sidx = s; D.rev = d;
    }
    enc_step<<<dim3(4, 64, 2), 256, 0, stream>>>(dd[0], dd[1]);
  }

  // ---- proj (bf16) + p0 (f32), then initial attention ----
  {
    PLeg proj = { ssH, ssL, H_, aSrth, aSrtl, H_, att_src_b, projbf, H_, 1, S_ * B_, H_, H_ };
    PLeg p0   = { ssH, ssL, H_, aStth, aSttl, H_, att_st_b,  pbuf,   H_, 0, B_,      H_, H_ };
    gemm_pl<<<dim3(2, 512, 2), 256, 0, stream>>>(proj, p0);
  }
  attend_k<<<B_, 256, 0, stream>>>(projbf, ssH, pbuf, att_v, ctxh, ctxl);

  // ---- decoder: ONE launch per step ----
  for (int t = 0; t < T_; t++) {
    DSP D;
    D.hPH = t ? hAllH + (size_t)(t - 1) * BH : ssH;
    D.hPL = t ? hAllL + (size_t)(t - 1) * BH : ssL;
    D.hPF = t ? hDecF[t & 1] : nullptr;
    D.hFo = hDecF[(t & 1) ^ 1];
    D.UH = dUth; D.UL = dUtl; D.CH = dWcth; D.CL = dWctl;
    D.sWH = aStth; D.sWL = aSttl;
    D.gxT = Td; D.bias = dec_b; D.stb = att_st_b; D.attv = att_v;
    D.ssH = ssH;
    D.projbf = projbf;
    D.hAH = hAllH + (size_t)t * BH; D.hAL = hAllL + (size_t)t * BH;
    D.ctxH = ctxh; D.ctxL = ctxl;
    D.ids = target_ids;
    D.t = t; D.last = (t == T_ - 1) ? 1 : 0;
    dec_step<<<256, 512, 0, stream>>>(D);
  }

  // ---- batched logits ----
  {
    PLeg LO = { hAllH, hAllL, H_, oWth, oWtl, H_, out_b, out, 0, 2, T_ * B_, VT_, H_ };
    gemm_pl<<<dim3(2, 512, 1), 256, 0, stream>>>(LO, LO);
  }
}

// Round 12
// 3251.247 us; speedup vs baseline: 3.7629x; 1.3206x over previous
//
#include <hip/hip_runtime.h>
#include <math.h>

#define B_  2048
#define S_  32
#define T_  32
#define D_  128
#define H_  256
#define G3  768
#define VT_ 256
#define BOW_ 1

typedef __attribute__((ext_vector_type(8))) short short8;
typedef __attribute__((ext_vector_type(4))) float f32x4;
typedef __attribute__((ext_vector_type(8))) unsigned short us8;
typedef unsigned short u16;

#define MFMA16 __builtin_amdgcn_mfma_f32_16x16x32_bf16

__device__ inline u16 f2bf(float x) {
  union { float f; unsigned u; } v; v.f = x;
  unsigned r = v.u + 0x7FFFu + ((v.u >> 16) & 1u);
  return (u16)(r >> 16);
}
__device__ inline float bf2f(u16 b) {
  union { unsigned u; float f; } v; v.u = ((unsigned)b) << 16; return v.f;
}
__device__ inline int swz(int r) { return ((r ^ (r >> 3)) & 7) << 3; }
__device__ inline float sigm(float x) { return 1.f / (1.f + expf(-x)); }

// ---------------- weight transpose + split ----------------
struct TMat { const float* src; u16* dhi; u16* dlo; int R; int C; int tile0; };
struct TPack { TMat m[10]; };

__global__ __launch_bounds__(256)
void wsplit_t(TPack P) {
  int bx = blockIdx.x;
  TMat M = P.m[0];
  #pragma unroll
  for (int i = 1; i < 10; i++) if (bx >= P.m[i].tile0) M = P.m[i];
  int ti = bx - M.tile0;
  int tilesR = M.R >> 6;
  int rt = ti % tilesR, ct = ti / tilesR;
  int r0 = rt * 64, c0 = ct * 64;
  __shared__ float ts[64][65];
  int tid = threadIdx.x;
  int cx = tid & 63, ry = tid >> 6;
  #pragma unroll
  for (int i = 0; i < 16; i++) {
    int r = ry * 16 + i;
    ts[r][cx] = M.src[(size_t)(r0 + r) * M.C + c0 + cx];
  }
  __syncthreads();
  int rx = tid & 63, cy = tid >> 6;
  #pragma unroll
  for (int i = 0; i < 16; i++) {
    int cc = cy * 16 + i;
    float v = ts[rx][cc];
    u16 hi = f2bf(v);
    size_t o = (size_t)(c0 + cc) * M.R + r0 + rx;
    M.dhi[o] = hi;
    M.dlo[o] = f2bf(v - bf2f(hi));
  }
}

__global__ __launch_bounds__(256)
void esplit(const float* a, const float* b, u16* ah, u16* al, u16* bh, u16* bl, int n) {
  int i = blockIdx.x * 256 + threadIdx.x;
  if (i >= 2 * n) return;
  const float* s = (i < n) ? a : b;
  u16* dh = (i < n) ? ah : bh;
  u16* dl = (i < n) ? al : bl;
  int j = (i < n) ? i : i - n;
  float v = s[j];
  u16 hi = f2bf(v);
  dh[j] = hi; dl[j] = f2bf(v - bf2f(hi));
}

// ---------------- plane GEMM ----------------
struct PLeg {
  const u16* Ahi; const u16* Alo; int lda;
  const u16* Bthi; const u16* Btlo; int ldb;
  const float* bias; void* C; int ldc; int cmode;  // 0=f32, 1=bf16, 2=logits-layout
  int M, N, K;
};

__global__ __launch_bounds__(256)
void gemm_pl(PLeg l0, PLeg l1) {
  PLeg L = blockIdx.z ? l1 : l0;
  int n0 = blockIdx.x * 128; if (n0 >= L.N) return;
  int m0 = blockIdx.y * 128; if (m0 >= L.M) return;
  __shared__ u16 As[128 * 64];
  __shared__ u16 Bs[128 * 64];
  int tid = threadIdx.x;
  int lane = tid & 63, wv = tid >> 6;
  int wr = (wv >> 1) * 64, wc = (wv & 1) * 64;
  int fr = lane & 15, fk = (lane >> 4) * 8;
  f32x4 acc[4][4];
  #pragma unroll
  for (int m = 0; m < 4; m++)
    #pragma unroll
    for (int n = 0; n < 4; n++) acc[m][n] = (f32x4){0.f, 0.f, 0.f, 0.f};

  int s_row = tid >> 1, s_part = tid & 1;

  for (int k0 = 0; k0 < L.K; k0 += 32) {
    if (k0) __syncthreads();
    int swA = swz(s_row);
    {
      const u16* src = (s_part ? L.Alo : L.Ahi) + (size_t)(m0 + s_row) * L.lda + k0;
      #pragma unroll
      for (int q = 0; q < 4; q++)
        *(us8*)&As[(s_row * 64 + s_part * 32 + q * 8) ^ swA] = *(const us8*)(src + q * 8);
    }
    {
      const u16* src = (s_part ? L.Btlo : L.Bthi) + (size_t)(n0 + s_row) * L.ldb + k0;
      #pragma unroll
      for (int q = 0; q < 4; q++)
        *(us8*)&Bs[(s_row * 64 + s_part * 32 + q * 8) ^ swA] = *(const us8*)(src + q * 8);
    }
    __syncthreads();
    short8 bhi[4], blo[4];
    #pragma unroll
    for (int n = 0; n < 4; n++) {
      int cc = wc + n * 16 + fr; int sw = swz(cc);
      bhi[n] = *(const short8*)&Bs[(cc * 64 + fk) ^ sw];
      blo[n] = *(const short8*)&Bs[(cc * 64 + 32 + fk) ^ sw];
    }
    #pragma unroll
    for (int m = 0; m < 4; m++) {
      int r = wr + m * 16 + fr; int sw = swz(r);
      short8 ahi = *(const short8*)&As[(r * 64 + fk) ^ sw];
      short8 alo = *(const short8*)&As[(r * 64 + 32 + fk) ^ sw];
      #pragma unroll
      for (int n = 0; n < 4; n++) {
        acc[m][n] = MFMA16(ahi, bhi[n], acc[m][n], 0, 0, 0);
        acc[m][n] = MFMA16(ahi, blo[n], acc[m][n], 0, 0, 0);
        acc[m][n] = MFMA16(alo, bhi[n], acc[m][n], 0, 0, 0);
      }
    }
  }
  int rbase = (lane >> 4) * 4;
  #pragma unroll
  for (int m = 0; m < 4; m++)
    #pragma unroll
    for (int rr = 0; rr < 4; rr++) {
      int row = m0 + wr + m * 16 + rbase + rr;
      #pragma unroll
      for (int n = 0; n < 4; n++) {
        int col = n0 + wc + n * 16 + fr;
        float v = acc[m][n][rr];
        if (L.bias) v += L.bias[col];
        if (L.cmode == 0)      ((float*)L.C)[(size_t)row * L.ldc + col] = v;
        else if (L.cmode == 1) ((u16*)L.C)[(size_t)row * L.ldc + col] = f2bf(v);
        else {
          size_t o = (((size_t)(row & (B_ - 1))) * T_ + (row >> 11)) * VT_ + col;
          ((float*)L.C)[o] = v;
        }
      }
    }
}

// ---------------- encoder step (r7 verbatim semantics) ----------------
struct EncD {
  const u16 *a0H, *a0L;
  const u16 *b0H, *b0L;
  const float *gxT;
  const float *bias0, *bias1;
  const float *hold;
  float *hnew;
  u16 *hh, *hl;
  u16 *ssH, *ssL;
  const int *ids;
  int ssmode;      // 1 store, 2 add
  int sidx, rev;
};

__global__ __launch_bounds__(256)
void enc_step(EncD d0, EncD d1) {
  EncD D = blockIdx.z ? d1 : d0;
  __shared__ __align__(16) u16 As[2 * 32 * 256];

  int m0 = blockIdx.y * 32;
  int tid = threadIdx.x;
  int lane = tid & 63, wv = tid >> 6;
  int fr = lane & 15, kq = lane >> 4;
  int jn = blockIdx.x * 64 + wv * 16 + fr;

  #pragma unroll
  for (int i = 0; i < 8; i++) {
    int s = tid + i * 256;
    int p = s >> 10;
    int rem = s & 1023;
    int row = rem >> 5;
    const u16* src = (p ? D.a0L : D.a0H) + (size_t)(m0 + row) * 256 + (rem & 31) * 8;
    *(us8*)&As[(s ^ (row & 7)) * 8] = *(const us8*)src;
  }
  __syncthreads();

  f32x4 acc[3], acc2[3];
  #pragma unroll
  for (int a = 0; a < 3; a++) { acc[a] = (f32x4){0.f,0.f,0.f,0.f}; acc2[a] = (f32x4){0.f,0.f,0.f,0.f}; }

  #pragma unroll
  for (int i = 0; i < 8; i++) {
    short8 ah[2], al[2];
    #pragma unroll
    for (int mf = 0; mf < 2; mf++) {
      int rp = mf * 16 + fr;
      int kb = i * 4 + kq;
      ah[mf] = *(const short8*)&As[((rp * 32 + kb) ^ (fr & 7)) * 8];
      al[mf] = *(const short8*)&As[((1024 + rp * 32 + kb) ^ (fr & 7)) * 8];
    }
    #pragma unroll
    for (int st = 0; st < 3; st++) {
      size_t ro = (size_t)(st * 256 + jn) * 256 + i * 32 + kq * 8;
      short8 bh = *(const short8*)(D.b0H + ro);
      short8 bl = *(const short8*)(D.b0L + ro);
      acc[st]  = MFMA16(ah[0], bh, acc[st], 0, 0, 0);
      acc[st]  = MFMA16(ah[0], bl, acc[st], 0, 0, 0);
      acc[st]  = MFMA16(al[0], bh, acc[st], 0, 0, 0);
      acc2[st] = MFMA16(ah[1], bh, acc2[st], 0, 0, 0);
      acc2[st] = MFMA16(ah[1], bl, acc2[st], 0, 0, 0);
      acc2[st] = MFMA16(al[1], bh, acc2[st], 0, 0, 0);
    }
  }

  float b0z = D.bias0[jn] + D.bias1[jn];
  float b0r = D.bias0[256 + jn] + D.bias1[256 + jn];
  float bxc = D.bias0[512 + jn];
  float bhc = D.bias1[512 + jn];
  int rbase = kq * 4;
  #pragma unroll
  for (int mf = 0; mf < 2; mf++)
    #pragma unroll
    for (int rr = 0; rr < 4; rr++) {
      int b = m0 + mf * 16 + rbase + rr;
      size_t o = (size_t)b * H_ + jn;
      int id = D.ids[b * S_ + (D.rev ? (S_ - 1 - D.sidx) : D.sidx)];
      const float* T = D.gxT + (size_t)id * G3;
      float az  = mf ? acc2[0][rr] : acc[0][rr];
      float ar  = mf ? acc2[1][rr] : acc[1][rr];
      float ahc = mf ? acc2[2][rr] : acc[2][rr];
      float z = sigm(az + T[jn] + b0z);
      float r = sigm(ar + T[256 + jn] + b0r);
      float c = tanhf(T[512 + jn] + bxc + r * (ahc + bhc));
      float hn = z * D.hold[o] + (1.f - z) * c;
      D.hnew[o] = hn;
      u16 hi = f2bf(hn);
      u16 lo = f2bf(hn - bf2f(hi));
      D.hh[o] = hi; D.hl[o] = lo;
      if (D.ssmode == 1) {
        D.ssH[o] = hi; D.ssL[o] = lo;
      } else {
        float v = bf2f(D.ssH[o]) + bf2f(D.ssL[o]) + hn;
        u16 vh = f2bf(v);
        D.ssH[o] = vh; D.ssL[o] = f2bf(v - bf2f(vh));
      }
    }
}

// ---------------- decoder gru (r7 gru_step<1> verbatim semantics) ----------------
struct GruD {
  const u16 *a0H, *a0L;   // h_{t-1} planes
  const u16 *a1H, *a1L;   // ctx planes
  const u16 *b0H, *b0L;   // U^T
  const u16 *b1H, *b1L;   // Wc^T
  const float *gxT;
  const float *bias;
  const float *hold;      // f32 (null at t=0 -> holdH/L)
  const u16 *holdH, *holdL;
  float *hnew;
  u16 *hh, *hl;
  const int *ids;
  int sidx;
};

__global__ __launch_bounds__(256)
void dec_gru(GruD D) {
  __shared__ __align__(16) u16 As[2 * 32 * 512];

  int m0 = blockIdx.y * 32;
  int tid = threadIdx.x;
  int lane = tid & 63, wv = tid >> 6;
  int fr = lane & 15, kq = lane >> 4;
  int jn = blockIdx.x * 32 + (wv & 1) * 16 + fr;
  int rb0 = (wv >> 1) * 16;

  #pragma unroll
  for (int i = 0; i < 16; i++) {
    int s = tid + i * 256;
    int p = s >> 11;
    int rem = s & 2047;
    int row = rem >> 6;
    int k = (rem & 63) * 8;
    const u16* src = (k < 256)
      ? (p ? D.a0L : D.a0H) + (size_t)(m0 + row) * 256 + k
      : (p ? D.a1L : D.a1H) + (size_t)(m0 + row) * 256 + (k - 256);
    *(us8*)&As[(s ^ (row & 7)) * 8] = *(const us8*)src;
  }
  __syncthreads();

  f32x4 acc[4];
  #pragma unroll
  for (int a = 0; a < 4; a++) acc[a] = (f32x4){0.f,0.f,0.f,0.f};

  #pragma unroll
  for (int i = 0; i < 16; i++) {
    const u16 *wbh, *wbl; int bk, ai2;
    if (i < 8) { wbh = D.b0H; wbl = D.b0L; bk = i * 32; ai2 = 2; }
    else       { wbh = D.b1H; wbl = D.b1L; bk = (i - 8) * 32; ai2 = 3; }
    int rp = rb0 + fr;
    int kb = i * 4 + kq;
    short8 ah = *(const short8*)&As[((rp * 64 + kb) ^ (fr & 7)) * 8];
    short8 al = *(const short8*)&As[((2048 + rp * 64 + kb) ^ (fr & 7)) * 8];
    #pragma unroll
    for (int st = 0; st < 3; st++) {
      size_t ro = (size_t)(st * 256 + jn) * 256 + bk + kq * 8;
      short8 bh = *(const short8*)(wbh + ro);
      short8 bl = *(const short8*)(wbl + ro);
      int ai = (st < 2) ? st : ai2;
      acc[ai] = MFMA16(ah, bh, acc[ai], 0, 0, 0);
      acc[ai] = MFMA16(ah, bl, acc[ai], 0, 0, 0);
      acc[ai] = MFMA16(al, bh, acc[ai], 0, 0, 0);
    }
  }

  float b0z = D.bias[jn] + D.bias[G3 + jn];
  float b0r = D.bias[256 + jn] + D.bias[G3 + 256 + jn];
  float bxc = D.bias[512 + jn];
  float bhc = D.bias[G3 + 512 + jn];
  int rbase = kq * 4;
  #pragma unroll
  for (int rr = 0; rr < 4; rr++) {
    int b = m0 + rb0 + rbase + rr;
    size_t o = (size_t)b * H_ + jn;
    int id = (D.sidx == 0) ? BOW_ : D.ids[b * T_ + D.sidx - 1];
    const float* T = D.gxT + (size_t)id * G3;
    float z = sigm(acc[0][rr] + T[jn] + b0z);
    float r = sigm(acc[1][rr] + T[256 + jn] + b0r);
    float c = tanhf(T[512 + jn] + bxc + acc[3][rr] + r * (acc[2][rr] + bhc));
    float hprev = D.hold ? D.hold[o] : (bf2f(D.holdH[o]) + bf2f(D.holdL[o]));
    float hn = z * hprev + (1.f - z) * c;
    D.hnew[o] = hn;
    u16 hi = f2bf(hn);
    D.hh[o] = hi; D.hl[o] = f2bf(hn - bf2f(hi));
  }
}

// ================= fused LP(MFMA) + attend: 256 blocks x 1024 threads =================
struct LAP {
  const u16 *hH, *hL;          // h planes [B][H]
  const u16 *sWH, *sWL;        // att_st^T planes [j][k]
  const float *stb, *attv;
  const u16 *projbf, *ssH;
  u16 *ctxH, *ctxL;
};

__global__ __launch_bounds__(1024)
void la_step(LAP P) {
  __shared__ __align__(16) u16 AH[16 * 256];   // 8 KB (16 rows x 32 k8)
  __shared__ __align__(16) u16 AL[16 * 256];   // 8 KB
  __shared__ float pS[8 * 256];                // 8 KB
  __shared__ float eS[8 * 32];                 // 1 KB
  const int tid = threadIdx.x;
  const int lane = tid & 63, w = tid >> 6;     // 16 waves
  const int fr = lane & 15, kq = lane >> 4;
  const int r0 = blockIdx.x * 8;

  // ---- stage h rows (8 rows, hi+lo), rows 8-15 zero: 1024 slots, 1/thread ----
  {
    int s = tid;
    int p = s >> 9;
    int rem = s & 511;
    int row = rem >> 5, k8 = rem & 31;
    us8 v = {0,0,0,0,0,0,0,0};
    if (row < 8)
      v = *(const us8*)((p ? P.hL : P.hH) + (size_t)(r0 + row) * 256 + k8 * 8);
    int slot = row * 32 + (k8 ^ (row & 7));
    if (p) *(us8*)&AL[slot * 8] = v;
    else   *(us8*)&AH[slot * 8] = v;
  }
  __syncthreads();

  // ---- LP: wave w owns j-tile w (j = w*16 + fr) ----
  f32x4 pa = (f32x4){0.f, 0.f, 0.f, 0.f};
  #pragma unroll
  for (int i = 0; i < 8; i++) {
    int slot = fr * 32 + ((i * 4 + kq) ^ (fr & 7));
    short8 ah = *(const short8*)&AH[slot * 8];
    short8 al = *(const short8*)&AL[slot * 8];
    size_t ro = (size_t)(w * 16 + fr) * 256 + i * 32 + kq * 8;
    short8 bh = *(const short8*)(P.sWH + ro);
    short8 bl = *(const short8*)(P.sWL + ro);
    pa = MFMA16(ah, bh, pa, 0, 0, 0);
    pa = MFMA16(ah, bl, pa, 0, 0, 0);
    pa = MFMA16(al, bh, pa, 0, 0, 0);
  }
  if (kq < 2) {
    #pragma unroll
    for (int rr = 0; rr < 4; rr++) {
      int row = kq * 4 + rr;
      int j = w * 16 + fr;
      pS[row * 256 + j] = pa[rr] + P.stb[j];
    }
  }
  __syncthreads();

  // ---- scores: wave w handles row (w&7), s-range (w>>3)*16..+16 ----
  {
    int row = w & 7;
    int gb = r0 + row;
    int sb = (w >> 3) * 16;
    float pq[4], vq[4];
    #pragma unroll
    for (int q = 0; q < 4; q++) {
      pq[q] = pS[row * 256 + q * 64 + lane];
      vq[q] = P.attv[q * 64 + lane];
    }
    #pragma unroll 4
    for (int s2 = 0; s2 < 16; s2++) {
      const u16* pr = P.projbf + ((size_t)(sb + s2) * B_ + gb) * 256;
      float part = 0.f;
      #pragma unroll
      for (int q = 0; q < 4; q++)
        part += tanhf(bf2f(pr[q * 64 + lane]) + pq[q]) * vq[q];
      #pragma unroll
      for (int off = 32; off; off >>= 1)
        part += __shfl_xor(part, off);
      if (lane == 0) eS[row * 32 + sb + s2] = part;
    }
  }
  __syncthreads();

  // ---- softmax + ctx: waves 0..7 (row = w) ----
  if (w < 8) {
    int gb = r0 + w;
    float sc[S_];
    #pragma unroll
    for (int s2 = 0; s2 < S_; s2++) sc[s2] = eS[w * 32 + s2];
    float m = -1e30f;
    #pragma unroll
    for (int s2 = 0; s2 < S_; s2++) m = fmaxf(m, sc[s2]);
    float den = 0.f;
    #pragma unroll
    for (int s2 = 0; s2 < S_; s2++) { sc[s2] = expf(sc[s2] - m); den += sc[s2]; }
    float inv = 1.f / den;
    float cacc[4] = {0.f, 0.f, 0.f, 0.f};
    #pragma unroll 8
    for (int s2 = 0; s2 < S_; s2++) {
      float wgt = sc[s2] * inv;
      const u16* sp = P.ssH + ((size_t)s2 * B_ + gb) * 256;
      #pragma unroll
      for (int q = 0; q < 4; q++)
        cacc[q] = fmaf(wgt, bf2f(sp[q * 64 + lane]), cacc[q]);
    }
    #pragma unroll
    for (int q = 0; q < 4; q++) {
      size_t o = (size_t)gb * H_ + q * 64 + lane;
      u16 hi = f2bf(cacc[q]);
      P.ctxH[o] = hi;
      P.ctxL[o] = f2bf(cacc[q] - bf2f(hi));
    }
  }
}

// ---------------- host ----------------
extern "C" void kernel_launch(void* const* d_in, const int* in_sizes, int n_in,
                              void* d_out, int out_size, void* d_ws, size_t ws_size,
                              hipStream_t stream) {
  const float* src_emb   = (const float*)d_in[0];
  const float* tgt_emb   = (const float*)d_in[1];
  const float* enc_f_W   = (const float*)d_in[2];
  const float* enc_f_U   = (const float*)d_in[3];
  const float* enc_f_b   = (const float*)d_in[4];
  const float* enc_b_W   = (const float*)d_in[5];
  const float* enc_b_U   = (const float*)d_in[6];
  const float* enc_b_b   = (const float*)d_in[7];
  const float* dec_W     = (const float*)d_in[8];
  const float* dec_U     = (const float*)d_in[9];
  const float* dec_b     = (const float*)d_in[10];
  const float* out_W     = (const float*)d_in[11];
  const float* out_b     = (const float*)d_in[12];
  const float* att_src_W = (const float*)d_in[13];
  const float* att_src_b = (const float*)d_in[14];
  const float* att_st_W  = (const float*)d_in[15];
  const float* att_st_b  = (const float*)d_in[16];
  const float* att_v     = (const float*)d_in[17];
  const int* source_ids  = (const int*)d_in[19];
  const int* target_ids  = (const int*)d_in[20];
  float* out = (float*)d_out;

  char* base = (char*)d_ws;
  size_t off = 0;
  auto allocB = [&](size_t bytes) { void* p = base + off; off = (off + bytes + 255) & ~255UL; return p; };
  const size_t BH = (size_t)B_ * H_;

  u16* ssH    = (u16*)allocB((size_t)S_ * BH * 2);
  u16* ssL    = (u16*)allocB((size_t)S_ * BH * 2);
  u16* projbf = (u16*)allocB((size_t)S_ * BH * 2);
  u16* ctxh = (u16*)allocB(BH * 2);
  u16* ctxl = (u16*)allocB(BH * 2);

  float* encF0 = (float*)allocB(2 * BH * 4);
  u16*  encPl0 = (u16*)allocB(4 * BH * 2);
  float* encF1 = (float*)allocB(2 * BH * 4);
  u16*  encPl1 = (u16*)allocB(4 * BH * 2);
  float* encF[2][2]  = { { encF0, encF0 + BH }, { encF1, encF1 + BH } };
  u16*  encH[2][2]   = { { encPl0, encPl0 + 2 * BH }, { encPl1, encPl1 + 2 * BH } };
  u16*  encL[2][2]   = { { encPl0 + BH, encPl0 + 3 * BH }, { encPl1 + BH, encPl1 + 3 * BH } };

  float* hDecF[2] = { (float*)allocB(BH * 4), (float*)allocB(BH * 4) };
  u16* hAllH = (u16*)allocB((size_t)T_ * BH * 2);
  u16* hAllL = (u16*)allocB((size_t)T_ * BH * 2);

  auto planes2 = [&](size_t n, u16*& h, u16*& l) { h = (u16*)allocB(n * 2); l = (u16*)allocB(n * 2); };
  u16 *UtFh,*UtFl,*UtBh,*UtBl,*WtFh,*WtFl,*WtBh,*WtBl;
  u16 *dUth,*dUtl,*dWcth,*dWctl,*dWxth,*dWxtl;
  u16 *oWth,*oWtl,*aStth,*aSttl,*aSrth,*aSrtl;
  u16 *sEh,*sEl,*tEh,*tEl;
  planes2((size_t)G3*H_, UtFh, UtFl);   planes2((size_t)G3*H_, UtBh, UtBl);
  planes2((size_t)G3*D_, WtFh, WtFl);   planes2((size_t)G3*D_, WtBh, WtBl);
  planes2((size_t)G3*H_, dUth, dUtl);   planes2((size_t)G3*H_, dWcth, dWctl);
  planes2((size_t)G3*D_, dWxth, dWxtl);
  planes2((size_t)H_*VT_, oWth, oWtl);
  planes2((size_t)H_*H_, aSrth, aSrtl);
  planes2((size_t)H_*H_, aStth, aSttl);
  planes2((size_t)VT_*D_, sEh, sEl);    planes2((size_t)VT_*D_, tEh, tEl);
  float* Tf = (float*)allocB((size_t)VT_ * G3 * 4);
  float* Tb = (float*)allocB((size_t)VT_ * G3 * 4);
  float* Td = (float*)allocB((size_t)VT_ * G3 * 4);

  TPack P;
  P.m[0] = { enc_f_U,          UtFh, UtFl, 256, 768, 0   };
  P.m[1] = { enc_b_U,          UtBh, UtBl, 256, 768, 48  };
  P.m[2] = { dec_U,            dUth, dUtl, 256, 768, 96  };
  P.m[3] = { dec_W + 128 * G3, dWcth, dWctl, 256, 768, 144 };
  P.m[4] = { enc_f_W,          WtFh, WtFl, 128, 768, 192 };
  P.m[5] = { enc_b_W,          WtBh, WtBl, 128, 768, 216 };
  P.m[6] = { dec_W,            dWxth, dWxtl, 128, 768, 240 };
  P.m[7] = { out_W,            oWth, oWtl, 256, 256, 264 };
  P.m[8] = { att_src_W,        aSrth, aSrtl, 256, 256, 280 };
  P.m[9] = { att_st_W,         aStth, aSttl, 256, 256, 296 };
  wsplit_t<<<312, 256, 0, stream>>>(P);
  esplit<<<(2 * VT_ * D_ + 255) / 256, 256, 0, stream>>>(src_emb, tgt_emb, sEh, sEl, tEh, tEl, VT_ * D_);

  // gx tables
  {
    PLeg tf = { sEh, sEl, D_, WtFh, WtFl, D_, nullptr, Tf, G3, 0, VT_, G3, D_ };
    PLeg tb = { sEh, sEl, D_, WtBh, WtBl, D_, nullptr, Tb, G3, 0, VT_, G3, D_ };
    gemm_pl<<<dim3(6, 2, 2), 256, 0, stream>>>(tf, tb);
    PLeg td = { tEh, tEl, D_, dWxth, dWxtl, D_, nullptr, Td, G3, 0, VT_, G3, D_ };
    gemm_pl<<<dim3(6, 2, 1), 256, 0, stream>>>(td, td);
  }

  hipMemsetAsync(encF0, 0, 2 * BH * 4, stream);
  hipMemsetAsync(encPl0, 0, 4 * BH * 2, stream);

  // ---- encoder ----
  for (int s = 0; s < S_; s++) {
    int p = s & 1;
    EncD dd[2];
    for (int d = 0; d < 2; d++) {
      EncD& D = dd[d];
      D.a0H = encH[p][d]; D.a0L = encL[p][d];
      D.b0H = d ? UtBh : UtFh; D.b0L = d ? UtBl : UtFl;
      D.gxT = d ? Tb : Tf;
      D.bias0 = d ? enc_b_b : enc_f_b;
      D.bias1 = (d ? enc_b_b : enc_f_b) + G3;
      D.hold = encF[p][d];
      D.hnew = encF[p ^ 1][d];
      D.hh = encH[p ^ 1][d]; D.hl = encL[p ^ 1][d];
      int pos = d ? (S_ - 1 - s) : s;
      D.ssH = ssH + (size_t)pos * BH; D.ssL = ssL + (size_t)pos * BH;
      D.ids = source_ids;
      D.ssmode = (s < S_ / 2) ? 1 : 2;
      D.sidx = s; D.rev = d;
    }
    enc_step<<<dim3(4, 64, 2), 256, 0, stream>>>(dd[0], dd[1]);
  }

  // ---- proj (bf16) ----
  {
    PLeg proj = { ssH, ssL, H_, aSrth, aSrtl, H_, att_src_b, projbf, H_, 1, S_ * B_, H_, H_ };
    gemm_pl<<<dim3(2, 512, 1), 256, 0, stream>>>(proj, proj);
  }

  // ---- initial attention (h0 = ss[0] planes) ----
  {
    LAP L = { ssH, ssL, aStth, aSttl, att_st_b, att_v, projbf, ssH, ctxh, ctxl };
    la_step<<<256, 1024, 0, stream>>>(L);
  }

  // ---- decoder: 2 launches per step ----
  for (int t = 0; t < T_; t++) {
    GruD D;
    D.a0H = t ? hAllH + (size_t)(t - 1) * BH : ssH;
    D.a0L = t ? hAllL + (size_t)(t - 1) * BH : ssL;
    D.a1H = ctxh; D.a1L = ctxl;
    D.b0H = dUth;  D.b0L = dUtl;
    D.b1H = dWcth; D.b1L = dWctl;
    D.gxT = Td; D.bias = dec_b;
    if (t == 0) { D.hold = nullptr; D.holdH = ssH; D.holdL = ssL; }
    else        { D.hold = hDecF[t & 1]; D.holdH = nullptr; D.holdL = nullptr; }
    D.hnew = hDecF[(t & 1) ^ 1];
    D.hh = hAllH + (size_t)t * BH; D.hl = hAllL + (size_t)t * BH;
    D.ids = target_ids;
    D.sidx = t;
    dec_gru<<<dim3(8, 64), 256, 0, stream>>>(D);

    if (t < T_ - 1) {
      LAP L = { hAllH + (size_t)t * BH, hAllL + (size_t)t * BH,
                aStth, aSttl, att_st_b, att_v, projbf, ssH, ctxh, ctxl };
      la_step<<<256, 1024, 0, stream>>>(L);
    }
  }

  // ---- batched logits ----
  {
    PLeg LO = { hAllH, hAllL, H_, oWth, oWtl, H_, out_b, out, 0, 2, T_ * B_, VT_, H_ };
    gemm_pl<<<dim3(2, 512, 1), 256, 0, stream>>>(LO, LO);
  }
}